// Round 8
// baseline (285.657 us; speedup 1.0000x reference)
//
#include <hip/hip_runtime.h>
#include <stdint.h>

#define DIMS 256
#define NT 4096
#define NROWS 65536
#define THETA 1.5e-4f

typedef float    f32x4_t __attribute__((ext_vector_type(4)));
typedef _Float16 f16x8_t __attribute__((ext_vector_type(8)));
typedef _Float16 f16x4_t __attribute__((ext_vector_type(4)));

// ---- kernel 0a: sx[n] = np.sum(flat*flat, axis=1) bit-exact (pairwise 256 = P128 + P128) ----
__global__ __launch_bounds__(256) void vq_sx(const float* __restrict__ x, float* __restrict__ sx){
  const int n = blockIdx.x * 256 + threadIdx.x;
  const int b = n >> 12, t = n & 4095;
  const float* xp = x + (size_t)b * DIMS * NT + t;
  float half[2];
  #pragma unroll
  for (int h = 0; h < 2; ++h){
    float r[8];
    #pragma unroll
    for (int j = 0; j < 8; ++j){
      float v = xp[(size_t)(h*128 + j) * NT];
      r[j] = __fmul_rn(v, v);
    }
    for (int i = 8; i < 128; i += 8){
      #pragma unroll
      for (int j = 0; j < 8; ++j){
        float v = xp[(size_t)(h*128 + i + j) * NT];
        r[j] = __fadd_rn(r[j], __fmul_rn(v, v));
      }
    }
    half[h] = __fadd_rn(__fadd_rn(__fadd_rn(r[0], r[1]), __fadd_rn(r[2], r[3])),
                        __fadd_rn(__fadd_rn(r[4], r[5]), __fadd_rn(r[6], r[7])));
  }
  sx[n] = __fadd_rn(half[0], half[1]);
}

// ---- kernel 0b: se[k] = np.sum(cb*cb, axis=1) bit-exact ----
__global__ void vq_se(const float* __restrict__ cb, float* __restrict__ se){
  const int k = blockIdx.x * 64 + threadIdx.x;
  const float* ep = cb + (size_t)k * DIMS;
  float half[2];
  #pragma unroll
  for (int h = 0; h < 2; ++h){
    float r[8];
    #pragma unroll
    for (int j = 0; j < 8; ++j){
      float v = ep[h*128 + j];
      r[j] = __fmul_rn(v, v);
    }
    for (int i = 8; i < 128; i += 8){
      #pragma unroll
      for (int j = 0; j < 8; ++j){
        float v = ep[h*128 + i + j];
        r[j] = __fadd_rn(r[j], __fmul_rn(v, v));
      }
    }
    half[h] = __fadd_rn(__fadd_rn(__fadd_rn(r[0], r[1]), __fadd_rn(r[2], r[3])),
                        __fadd_rn(__fadd_rn(r[4], r[5]), __fadd_rn(r[6], r[7])));
  }
  se[k] = __fadd_rn(half[0], half[1]);
}

// ---- kernel 0c: cb16[k][c] = (_Float16)(cb[k][c] * 512) once (pure-pow2 scale) ----
__global__ __launch_bounds__(256) void vq_cvt(const float* __restrict__ cb, _Float16* __restrict__ cb16){
  const int i = (blockIdx.x * 256 + threadIdx.x) * 4;
  float4 v = *(const float4*)(cb + i);
  f16x4_t p;
  p.x = (_Float16)(v.x * 512.f);
  p.y = (_Float16)(v.y * 512.f);
  p.z = (_Float16)(v.z * 512.f);
  p.w = (_Float16)(v.w * 512.f);
  *(f16x4_t*)(cb16 + i) = p;
}

// ================= kernel 1: approx scores, B direct from L2, one barrier =================
// 64 rows/block x 1024 codes; kt tiles of 256 codes; score = se_k - dot/256.
// A staged once in LDS; B frags double-set prefetched straight from cb16 (L2-resident).

#define T2I(v, i, v1, i1, v2) { \
  bool lt = (v) < (v1); \
  (v2) = lt ? (v1) : fminf((v2), (v)); \
  (i1) = lt ? (i) : (i1); \
  (v1) = lt ? (v) : (v1); }

#define DECL_T2(M,R) \
  float b1_##M##R = 3.4e38f, b2_##M##R = 3.4e38f; int bi_##M##R = 0x7fffffff;

#define FOLD(M,R) { \
  float v; \
  v = fmaf(a##M##0[R], NEGI, ec0); T2I(v, kc0, b1_##M##R, bi_##M##R, b2_##M##R); \
  v = fmaf(a##M##1[R], NEGI, ec1); T2I(v, kc1, b1_##M##R, bi_##M##R, b2_##M##R); \
  v = fmaf(a##M##2[R], NEGI, ec2); T2I(v, kc2, b1_##M##R, bi_##M##R, b2_##M##R); \
  v = fmaf(a##M##3[R], NEGI, ec3); T2I(v, kc3, b1_##M##R, bi_##M##R, b2_##M##R); }

#define LOADB(S, KT, CC) { \
  const _Float16* p_ = bp + (size_t)((KT)*256*DIMS + (CC)*32); \
  b##S##0 = *(const f16x8_t*)(p_); \
  b##S##1 = *(const f16x8_t*)(p_ + 16*DIMS); \
  b##S##2 = *(const f16x8_t*)(p_ + 32*DIMS); \
  b##S##3 = *(const f16x8_t*)(p_ + 48*DIMS); }

#define MFMA_ROW(M, CC, S) { \
  f16x8_t ah = *(const f16x8_t*)&Ah[(M)*16 + fr][(CC)*32 + fq*8]; \
  a##M##0 = __builtin_amdgcn_mfma_f32_16x16x32_f16(ah, b##S##0, a##M##0, 0, 0, 0); \
  a##M##1 = __builtin_amdgcn_mfma_f32_16x16x32_f16(ah, b##S##1, a##M##1, 0, 0, 0); \
  a##M##2 = __builtin_amdgcn_mfma_f32_16x16x32_f16(ah, b##S##2, a##M##2, 0, 0, 0); \
  a##M##3 = __builtin_amdgcn_mfma_f32_16x16x32_f16(ah, b##S##3, a##M##3, 0, 0, 0); }

#define CC_STEP(CC, USE, OTH) { \
  if ((CC) < 7) { LOADB(OTH, kt, (CC)+1) } \
  else if (kt < 3) { LOADB(OTH, kt+1, 0) } \
  MFMA_ROW(0, CC, USE) MFMA_ROW(1, CC, USE) MFMA_ROW(2, CC, USE) MFMA_ROW(3, CC, USE) }

#define MSTEP(MK) { \
  float ov1 = __shfl_xor(v1, MK); int oi1 = __shfl_xor(i1, MK); float ov2 = __shfl_xor(v2, MK); \
  bool tk = ov1 < v1; \
  v2 = tk ? fminf(v1, ov2) : fminf(v2, ov1); \
  i1 = tk ? oi1 : i1; \
  v1 = tk ? ov1 : v1; }

#define MERGE(M,R) { \
  float v1 = b1_##M##R, v2 = b2_##M##R; int i1 = bi_##M##R; \
  MSTEP(1) MSTEP(2) MSTEP(4) MSTEP(8) \
  if (fr == 0) comb[(M)*16 + fq*4 + (R)][wc] = make_float4(v1, __int_as_float(i1), v2, 0.f); }

__global__ __launch_bounds__(256, 2) void vq_scores(
    const float* __restrict__ x, const _Float16* __restrict__ cb16,
    const float* __restrict__ se, int* __restrict__ idx, float* __restrict__ out2,
    unsigned* __restrict__ wl, unsigned* __restrict__ cnt)
{
  __shared__ _Float16 Ah[64][264];        // 33792 B, row stride 132 dw === 4 (mod 32)
  __shared__ float4   comb[64][4];        //  4096 B   -> total 37888 B, 3 blocks/CU

  const int tid  = threadIdx.x;
  const int lane = tid & 63;
  const int wc   = tid >> 6;              // wave -> 64-code stripe within a 256-code kt tile
  const int fr   = lane & 15;
  const int fq   = lane >> 4;
  const int n0   = blockIdx.x * 64;
  const int bb   = n0 >> 12;
  const int t0   = n0 & 4095;
  const float NEGI = -1.0f/256.0f;

  // per-lane B base: code wc*64 + fr (+cf*16 via imm), K offset fq*8
  const _Float16* bp = cb16 + (size_t)(wc*64 + fr) * DIMS + fq*8;

  f16x8_t bA0, bA1, bA2, bA3, bB0, bB1, bB2, bB3;
  LOADB(A, 0, 0)    // issue first frags before A staging: overlap with HBM reads

  // ---- stage A once: 64 rows x 256 c, fp16 ----
  {
    const int dup = tid >> 7;                 // 0..1 -> c chunks 0-3 / 4-7
    const int c4  = tid & 7;                  // c quad within chunk
    const int tt  = ((tid >> 3) & 15) << 2;   // 4-row group
    #pragma unroll
    for (int cc2 = 0; cc2 < 4; ++cc2){
      const int c0 = (dup*4 + cc2) * 32;
      const float* xp = x + ((size_t)(bb*DIMS + c0 + c4*4))*NT + t0 + tt;
      float4 va0 = *(const float4*)(xp);
      float4 va1 = *(const float4*)(xp + NT);
      float4 va2 = *(const float4*)(xp + 2*NT);
      float4 va3 = *(const float4*)(xp + 3*NT);
      #pragma unroll
      for (int j = 0; j < 4; ++j){
        f16x4_t p;
        p.x = (_Float16)((&va0.x)[j]);
        p.y = (_Float16)((&va1.x)[j]);
        p.z = (_Float16)((&va2.x)[j]);
        p.w = (_Float16)((&va3.x)[j]);
        *(f16x4_t*)&Ah[tt + j][c0 + c4*4] = p;
      }
    }
  }
  comb[tid >> 2][tid & 3] = make_float4(3.4e38f, __int_as_float(0x7fffffff), 3.4e38f, 0.f);

  // named accumulators (16 x f32x4)
  const f32x4_t Z = {0.f, 0.f, 0.f, 0.f};
  f32x4_t a00=Z,a01=Z,a02=Z,a03=Z, a10=Z,a11=Z,a12=Z,a13=Z,
          a20=Z,a21=Z,a22=Z,a23=Z, a30=Z,a31=Z,a32=Z,a33=Z;
  // named top-2 state (16 rows per thread)
  DECL_T2(0,0) DECL_T2(0,1) DECL_T2(0,2) DECL_T2(0,3)
  DECL_T2(1,0) DECL_T2(1,1) DECL_T2(1,2) DECL_T2(1,3)
  DECL_T2(2,0) DECL_T2(2,1) DECL_T2(2,2) DECL_T2(2,3)
  DECL_T2(3,0) DECL_T2(3,1) DECL_T2(3,2) DECL_T2(3,3)

  __syncthreads();   // the only barrier: A tile visible to all waves

  for (int kt = 0; kt < 4; ++kt){
    CC_STEP(0, A, B) CC_STEP(1, B, A) CC_STEP(2, A, B) CC_STEP(3, B, A)
    CC_STEP(4, A, B) CC_STEP(5, B, A) CC_STEP(6, A, B) CC_STEP(7, B, A)

    // fold this kt's 64 codes into the running top-2 (all named scalars)
    const int kb  = kt*256 + wc*64 + fr;
    const int kc0 = kb, kc1 = kb + 16, kc2 = kb + 32, kc3 = kb + 48;
    const float ec0 = se[kc0], ec1 = se[kc1], ec2 = se[kc2], ec3 = se[kc3];
    FOLD(0,0) FOLD(0,1) FOLD(0,2) FOLD(0,3)
    FOLD(1,0) FOLD(1,1) FOLD(1,2) FOLD(1,3)
    FOLD(2,0) FOLD(2,1) FOLD(2,2) FOLD(2,3)
    FOLD(3,0) FOLD(3,1) FOLD(3,2) FOLD(3,3)
    a00=Z;a01=Z;a02=Z;a03=Z; a10=Z;a11=Z;a12=Z;a13=Z;
    a20=Z;a21=Z;a22=Z;a23=Z; a30=Z;a31=Z;a32=Z;a33=Z;
  }

  // cross-lane (fr) merge, then cross-wave merge via LDS
  MERGE(0,0) MERGE(0,1) MERGE(0,2) MERGE(0,3)
  MERGE(1,0) MERGE(1,1) MERGE(1,2) MERGE(1,3)
  MERGE(2,0) MERGE(2,1) MERGE(2,2) MERGE(2,3)
  MERGE(3,0) MERGE(3,1) MERGE(3,2) MERGE(3,3)
  __syncthreads();
  if (tid < 64){
    float4 p = comb[tid][0];
    float v1 = p.x, v2 = p.z;
    int   i1 = __float_as_int(p.y);
    #pragma unroll
    for (int w = 1; w < 4; ++w){
      p = comb[tid][w];
      bool tk = p.x < v1;
      v2 = tk ? fminf(v1, p.z) : fminf(v2, p.x);
      i1 = tk ? __float_as_int(p.y) : i1;
      v1 = tk ? p.x : v1;
    }
    const int r = n0 + tid;
    idx[r]  = i1;
    out2[r] = (float)i1;
    if (!(v2 - v1 >= THETA)){
      unsigned pos = atomicAdd(cnt, 1u);
      wl[pos] = (unsigned)r;
    }
  }
}

// ---- kernel 3: exact fp32-numpy-emulated full re-scan of flagged rows (8 rows/block) ----
__global__ __launch_bounds__(256) void vq_refine(
    const float* __restrict__ x, const float* __restrict__ cb,
    const float* __restrict__ sx, const float* __restrict__ se,
    const unsigned* __restrict__ wl, const unsigned* __restrict__ cnt,
    int* __restrict__ idx, float* __restrict__ out2)
{
  __shared__ float eT[8][1024];   // 32 KiB transposed codebook chunk
  __shared__ float xs[DIMS][8];   // 8 KiB
  __shared__ int   rows_s[8];
  __shared__ float sxs[8];
  __shared__ float wv[4][8];
  __shared__ int   wi[4][8];

  const unsigned n = *cnt;
  const unsigned groups = (n + 7u) >> 3;
  const int tid  = threadIdx.x;
  const int lane = tid & 63;
  const int wid  = tid >> 6;

  for (unsigned g = blockIdx.x; g < groups; g += gridDim.x){
    __syncthreads();   // protect rows_s/xs/wv reuse across groups
    if (tid < 8){
      unsigned e = g*8u + (unsigned)tid;
      int row = (int)wl[e < n ? e : (n - 1u)];
      rows_s[tid] = row;
      sxs[tid] = sx[row];
    }
    __syncthreads();
    // stage x rows (scattered gather along c)
    #pragma unroll
    for (int rep = 0; rep < 8; ++rep){
      int id = rep * 256 + tid;
      int c = id >> 3, r = id & 7;
      int row = rows_s[r];
      int b = row >> 12, t = row & 4095;
      xs[c][r] = x[((size_t)(b*DIMS + c))*NT + t];
    }

    float s[8][4];
    #pragma unroll
    for (int r = 0; r < 8; ++r)
      #pragma unroll
      for (int u = 0; u < 4; ++u) s[r][u] = 0.f;

    for (int c0 = 0; c0 < DIMS; c0 += 8){
      __syncthreads();
      #pragma unroll
      for (int rep = 0; rep < 8; ++rep){
        int id2 = rep * 256 + tid;
        int k = id2 >> 1, q = id2 & 1;
        float4 v = *(const float4*)&cb[(size_t)k * DIMS + c0 + q * 4];
        eT[q*4 + 0][k] = v.x; eT[q*4 + 1][k] = v.y;
        eT[q*4 + 2][k] = v.z; eT[q*4 + 3][k] = v.w;
      }
      __syncthreads();
      #pragma unroll
      for (int cc = 0; cc < 8; ++cc){
        float4 ev = *(const float4*)&eT[cc][wid*256 + lane*4];
        #pragma unroll
        for (int r = 0; r < 8; ++r){
          float xv = xs[c0 + cc][r];
          s[r][0] = fmaf(xv, ev.x, s[r][0]);
          s[r][1] = fmaf(xv, ev.y, s[r][1]);
          s[r][2] = fmaf(xv, ev.z, s[r][2]);
          s[r][3] = fmaf(xv, ev.w, s[r][3]);
        }
      }
    }

    float4 sek = *(const float4*)&se[wid*256 + lane*4];
    #pragma unroll
    for (int r = 0; r < 8; ++r){
      const float sxv = sxs[r];
      float bv = 3.4e38f; int bi = 0x7fffffff;
      #pragma unroll
      for (int u = 0; u < 4; ++u){
        float d = __fsub_rn(__fadd_rn(sxv, (&sek.x)[u]),
                            __fadd_rn(s[r][u], s[r][u]));
        int k = wid*256 + lane*4 + u;
        if (d < bv || (d == bv && k < bi)) { bv = d; bi = k; }
      }
      #pragma unroll
      for (int m = 1; m < 64; m <<= 1){
        float ov = __shfl_xor(bv, m);
        int   oi = __shfl_xor(bi, m);
        if (ov < bv || (ov == bv && oi < bi)) { bv = ov; bi = oi; }
      }
      if (lane == 0){ wv[wid][r] = bv; wi[wid][r] = bi; }
    }
    __syncthreads();
    if (tid < 8){
      const int r = tid;
      float bv = wv[0][r]; int bi = wi[0][r];
      #pragma unroll
      for (int w = 1; w < 4; ++w){
        float ov = wv[w][r]; int oi = wi[w][r];
        if (ov < bv || (ov == bv && oi < bi)) { bv = ov; bi = oi; }
      }
      if (g*8u + (unsigned)r < n){
        int row = rows_s[r];
        idx[row]  = bi;
        out2[row] = (float)bi;
      }
    }
  }
}

// ---- kernel 4: gather quantized (== quantized_st) via LDS codebook column, + loss ----
__global__ __launch_bounds__(256) void vq_gather(
    const float* __restrict__ x, const float* __restrict__ cb,
    const int* __restrict__ idx, float* __restrict__ out0, double* __restrict__ acc)
{
  __shared__ float col[1024];
  const int bc = blockIdx.x;          // b*256 + c
  const int bb = bc >> 8;
  const int c  = bc & 255;
  #pragma unroll
  for (int kk = 0; kk < 4; ++kk)
    col[kk*256 + threadIdx.x] = cb[(size_t)(kk*256 + threadIdx.x) * DIMS + c];
  __syncthreads();

  const float* xr = x + (size_t)bc * NT;
  float* orow = out0 + (size_t)bc * NT;
  const int* ir = idx + bb * NT;
  float s = 0.f;
  #pragma unroll
  for (int j = 0; j < 4; ++j){
    const int t = (threadIdx.x << 2) + (j << 10);
    float4 xv = *(const float4*)(xr + t);
    int4  iv  = *(const int4*)(ir + t);
    float4 q;
    q.x = col[iv.x];
    q.y = col[iv.y];
    q.z = col[iv.z];
    q.w = col[iv.w];
    float dx = q.x - xv.x, dy = q.y - xv.y, dz = q.z - xv.z, dw = q.w - xv.w;
    s += dx*dx + dy*dy + dz*dz + dw*dw;
    *(float4*)(orow + t) = q;
  }
  #pragma unroll
  for (int m = 1; m < 64; m <<= 1) s += __shfl_xor(s, m);
  __shared__ float wsum[4];
  if ((threadIdx.x & 63) == 0) wsum[threadIdx.x >> 6] = s;
  __syncthreads();
  if (threadIdx.x == 0){
    double tot = (double)wsum[0] + (double)wsum[1] + (double)wsum[2] + (double)wsum[3];
    atomicAdd(acc, tot);
  }
}

__global__ void vq_final(const double* __restrict__ acc, float* __restrict__ out1){
  *out1 = (float)(1.25 * (*acc) * (1.0 / 16777216.0));
}

extern "C" void kernel_launch(void* const* d_in, const int* in_sizes, int n_in,
                              void* d_out, int out_size, void* d_ws, size_t ws_size,
                              hipStream_t stream)
{
  const float* x  = (const float*)d_in[0];
  const float* cb = (const float*)d_in[1];
  float* out  = (float*)d_out;
  float* out0 = out;
  float* out1 = out + (size_t)16777216;   // vq_loss
  float* out2 = out + (size_t)16777217;   // indices as float [65536]

  char* ws = (char*)d_ws;
  double*   acc  = (double*)(ws + 0);
  unsigned* cnt  = (unsigned*)(ws + 8);
  float*    se   = (float*)(ws + 64);       // 4 KiB
  float*    sx   = (float*)(ws + 4160);     // 256 KiB
  int*      idx  = (int*)(ws + 266304);     // 256 KiB
  _Float16* cb16 = (_Float16*)(ws + 528448);// 512 KiB fp16 codebook (x512)

  // worklist lives in the out0 region (overwritten later by vq_gather):
  unsigned* wl = (unsigned*)(out + (size_t)4*1024*1024);   // at 16 MiB, 256 KiB

  hipMemsetAsync(d_ws, 0, 16, stream);     // zero loss accumulator + worklist count
  vq_sx    <<<dim3(256),  dim3(256), 0, stream>>>(x, sx);
  vq_se    <<<dim3(16),   dim3(64),  0, stream>>>(cb, se);
  vq_cvt   <<<dim3(256),  dim3(256), 0, stream>>>(cb, cb16);
  vq_scores<<<dim3(1024), dim3(256), 0, stream>>>(x, cb16, se, idx, out2, wl, cnt);
  vq_refine<<<dim3(512),  dim3(256), 0, stream>>>(x, cb, sx, se, wl, cnt, idx, out2);
  vq_gather<<<dim3(4096), dim3(256), 0, stream>>>(x, cb, idx, out0, acc);
  vq_final <<<dim3(1),    dim3(1),   0, stream>>>(acc, out1);
}

// Round 9
// 234.016 us; speedup vs baseline: 1.2207x; 1.2207x over previous
//
#include <hip/hip_runtime.h>
#include <stdint.h>

#define DIMS 256
#define NT 4096
#define NROWS 65536
#define THETA 1.5e-4f

typedef float    f32x4_t __attribute__((ext_vector_type(4)));
typedef _Float16 f16x8_t __attribute__((ext_vector_type(8)));
typedef _Float16 f16x4_t __attribute__((ext_vector_type(4)));

// ---- kernel 0a: sx[n] = np.sum(flat*flat, axis=1) bit-exact (pairwise 256 = P128 + P128) ----
__global__ __launch_bounds__(256) void vq_sx(const float* __restrict__ x, float* __restrict__ sx){
  const int n = blockIdx.x * 256 + threadIdx.x;
  const int b = n >> 12, t = n & 4095;
  const float* xp = x + (size_t)b * DIMS * NT + t;
  float half[2];
  #pragma unroll
  for (int h = 0; h < 2; ++h){
    float r[8];
    #pragma unroll
    for (int j = 0; j < 8; ++j){
      float v = xp[(size_t)(h*128 + j) * NT];
      r[j] = __fmul_rn(v, v);
    }
    for (int i = 8; i < 128; i += 8){
      #pragma unroll
      for (int j = 0; j < 8; ++j){
        float v = xp[(size_t)(h*128 + i + j) * NT];
        r[j] = __fadd_rn(r[j], __fmul_rn(v, v));
      }
    }
    half[h] = __fadd_rn(__fadd_rn(__fadd_rn(r[0], r[1]), __fadd_rn(r[2], r[3])),
                        __fadd_rn(__fadd_rn(r[4], r[5]), __fadd_rn(r[6], r[7])));
  }
  sx[n] = __fadd_rn(half[0], half[1]);
}

// ---- kernel 0b: se[k] = np.sum(cb*cb, axis=1) bit-exact ----
__global__ void vq_se(const float* __restrict__ cb, float* __restrict__ se){
  const int k = blockIdx.x * 64 + threadIdx.x;
  const float* ep = cb + (size_t)k * DIMS;
  float half[2];
  #pragma unroll
  for (int h = 0; h < 2; ++h){
    float r[8];
    #pragma unroll
    for (int j = 0; j < 8; ++j){
      float v = ep[h*128 + j];
      r[j] = __fmul_rn(v, v);
    }
    for (int i = 8; i < 128; i += 8){
      #pragma unroll
      for (int j = 0; j < 8; ++j){
        float v = ep[h*128 + i + j];
        r[j] = __fadd_rn(r[j], __fmul_rn(v, v));
      }
    }
    half[h] = __fadd_rn(__fadd_rn(__fadd_rn(r[0], r[1]), __fadd_rn(r[2], r[3])),
                        __fadd_rn(__fadd_rn(r[4], r[5]), __fadd_rn(r[6], r[7])));
  }
  se[k] = __fadd_rn(half[0], half[1]);
}

// ---- kernel 0c: cb16[k][c] = (_Float16)(cb[k][c] * 512) once (pure-pow2 scale) ----
__global__ __launch_bounds__(256) void vq_cvt(const float* __restrict__ cb, _Float16* __restrict__ cb16){
  const int i = (blockIdx.x * 256 + threadIdx.x) * 4;
  float4 v = *(const float4*)(cb + i);
  f16x4_t p;
  p.x = (_Float16)(v.x * 512.f);
  p.y = (_Float16)(v.y * 512.f);
  p.z = (_Float16)(v.z * 512.f);
  p.w = (_Float16)(v.w * 512.f);
  *(f16x4_t*)(cb16 + i) = p;
}

// ================= kernel 1: approx scores, B direct from L2, one barrier =================
// 64 rows/block x 1024 codes; kt tiles of 256 codes; score v = se_k - 2*dot.
// Loss fused: unflagged rows contribute sx[r] + v1 (== ||x-e||^2 to ~2e-5) to acc.

#define T2I(v, i, v1, i1, v2) { \
  bool lt = (v) < (v1); \
  (v2) = lt ? (v1) : fminf((v2), (v)); \
  (i1) = lt ? (i) : (i1); \
  (v1) = lt ? (v) : (v1); }

#define DECL_T2(M,R) \
  float b1_##M##R = 3.4e38f, b2_##M##R = 3.4e38f; int bi_##M##R = 0x7fffffff;

#define FOLD(M,R) { \
  float v; \
  v = fmaf(a##M##0[R], NEGI, ec0); T2I(v, kc0, b1_##M##R, bi_##M##R, b2_##M##R); \
  v = fmaf(a##M##1[R], NEGI, ec1); T2I(v, kc1, b1_##M##R, bi_##M##R, b2_##M##R); \
  v = fmaf(a##M##2[R], NEGI, ec2); T2I(v, kc2, b1_##M##R, bi_##M##R, b2_##M##R); \
  v = fmaf(a##M##3[R], NEGI, ec3); T2I(v, kc3, b1_##M##R, bi_##M##R, b2_##M##R); }

#define LOADB(S, KT, CC) { \
  const _Float16* p_ = bp + (size_t)((KT)*256*DIMS + (CC)*32); \
  b##S##0 = *(const f16x8_t*)(p_); \
  b##S##1 = *(const f16x8_t*)(p_ + 16*DIMS); \
  b##S##2 = *(const f16x8_t*)(p_ + 32*DIMS); \
  b##S##3 = *(const f16x8_t*)(p_ + 48*DIMS); }

#define MFMA_ROW(M, CC, S) { \
  f16x8_t ah = *(const f16x8_t*)&Ah[(M)*16 + fr][(CC)*32 + fq*8]; \
  a##M##0 = __builtin_amdgcn_mfma_f32_16x16x32_f16(ah, b##S##0, a##M##0, 0, 0, 0); \
  a##M##1 = __builtin_amdgcn_mfma_f32_16x16x32_f16(ah, b##S##1, a##M##1, 0, 0, 0); \
  a##M##2 = __builtin_amdgcn_mfma_f32_16x16x32_f16(ah, b##S##2, a##M##2, 0, 0, 0); \
  a##M##3 = __builtin_amdgcn_mfma_f32_16x16x32_f16(ah, b##S##3, a##M##3, 0, 0, 0); }

#define CC_STEP(CC, USE, OTH) { \
  if ((CC) < 7) { LOADB(OTH, kt, (CC)+1) } \
  else if (kt < 3) { LOADB(OTH, kt+1, 0) } \
  MFMA_ROW(0, CC, USE) MFMA_ROW(1, CC, USE) MFMA_ROW(2, CC, USE) MFMA_ROW(3, CC, USE) }

#define MSTEP(MK) { \
  float ov1 = __shfl_xor(v1, MK); int oi1 = __shfl_xor(i1, MK); float ov2 = __shfl_xor(v2, MK); \
  bool tk = ov1 < v1; \
  v2 = tk ? fminf(v1, ov2) : fminf(v2, ov1); \
  i1 = tk ? oi1 : i1; \
  v1 = tk ? ov1 : v1; }

#define MERGE(M,R) { \
  float v1 = b1_##M##R, v2 = b2_##M##R; int i1 = bi_##M##R; \
  MSTEP(1) MSTEP(2) MSTEP(4) MSTEP(8) \
  if (fr == 0) comb[(M)*16 + fq*4 + (R)][wc] = make_float4(v1, __int_as_float(i1), v2, 0.f); }

__global__ __launch_bounds__(256, 1) void vq_scores(
    const float* __restrict__ x, const _Float16* __restrict__ cb16,
    const float* __restrict__ se, const float* __restrict__ sx,
    int* __restrict__ idx, float* __restrict__ out2,
    unsigned* __restrict__ wl, unsigned* __restrict__ cnt, double* __restrict__ accd)
{
  __shared__ _Float16 Ah[64][264];        // 33792 B, row stride 132 dw === 4 (mod 32)
  __shared__ float4   comb[64][4];        //  4096 B   -> total 37888 B

  const int tid  = threadIdx.x;
  const int lane = tid & 63;
  const int wc   = tid >> 6;              // wave -> 64-code stripe within a 256-code kt tile
  const int fr   = lane & 15;
  const int fq   = lane >> 4;
  const int n0   = blockIdx.x * 64;
  const int bb   = n0 >> 12;
  const int t0   = n0 & 4095;
  const float NEGI = -1.0f/256.0f;

  // per-lane B base: code wc*64 + fr (+cf*16 via stride), K offset fq*8
  const _Float16* bp = cb16 + (size_t)(wc*64 + fr) * DIMS + fq*8;

  f16x8_t bA0, bA1, bA2, bA3, bB0, bB1, bB2, bB3;
  LOADB(A, 0, 0)    // issue first frags before A staging: overlap with HBM reads

  // ---- stage A once: 64 rows x 256 c, fp16 ----
  {
    const int dup = tid >> 7;                 // 0..1 -> c chunks 0-3 / 4-7
    const int c4  = tid & 7;                  // c quad within chunk
    const int tt  = ((tid >> 3) & 15) << 2;   // 4-row group
    #pragma unroll
    for (int cc2 = 0; cc2 < 4; ++cc2){
      const int c0 = (dup*4 + cc2) * 32;
      const float* xp = x + ((size_t)(bb*DIMS + c0 + c4*4))*NT + t0 + tt;
      float4 va0 = *(const float4*)(xp);
      float4 va1 = *(const float4*)(xp + NT);
      float4 va2 = *(const float4*)(xp + 2*NT);
      float4 va3 = *(const float4*)(xp + 3*NT);
      #pragma unroll
      for (int j = 0; j < 4; ++j){
        f16x4_t p;
        p.x = (_Float16)((&va0.x)[j]);
        p.y = (_Float16)((&va1.x)[j]);
        p.z = (_Float16)((&va2.x)[j]);
        p.w = (_Float16)((&va3.x)[j]);
        *(f16x4_t*)&Ah[tt + j][c0 + c4*4] = p;
      }
    }
  }
  comb[tid >> 2][tid & 3] = make_float4(3.4e38f, __int_as_float(0x7fffffff), 3.4e38f, 0.f);

  // named accumulators (16 x f32x4)
  const f32x4_t Z = {0.f, 0.f, 0.f, 0.f};
  f32x4_t a00=Z,a01=Z,a02=Z,a03=Z, a10=Z,a11=Z,a12=Z,a13=Z,
          a20=Z,a21=Z,a22=Z,a23=Z, a30=Z,a31=Z,a32=Z,a33=Z;
  // named top-2 state (16 rows per thread)
  DECL_T2(0,0) DECL_T2(0,1) DECL_T2(0,2) DECL_T2(0,3)
  DECL_T2(1,0) DECL_T2(1,1) DECL_T2(1,2) DECL_T2(1,3)
  DECL_T2(2,0) DECL_T2(2,1) DECL_T2(2,2) DECL_T2(2,3)
  DECL_T2(3,0) DECL_T2(3,1) DECL_T2(3,2) DECL_T2(3,3)

  __syncthreads();   // the only barrier: A tile visible to all waves

  for (int kt = 0; kt < 4; ++kt){
    CC_STEP(0, A, B) CC_STEP(1, B, A) CC_STEP(2, A, B) CC_STEP(3, B, A)
    CC_STEP(4, A, B) CC_STEP(5, B, A) CC_STEP(6, A, B) CC_STEP(7, B, A)

    // fold this kt's 64 codes into the running top-2 (all named scalars)
    const int kb  = kt*256 + wc*64 + fr;
    const int kc0 = kb, kc1 = kb + 16, kc2 = kb + 32, kc3 = kb + 48;
    const float ec0 = se[kc0], ec1 = se[kc1], ec2 = se[kc2], ec3 = se[kc3];
    FOLD(0,0) FOLD(0,1) FOLD(0,2) FOLD(0,3)
    FOLD(1,0) FOLD(1,1) FOLD(1,2) FOLD(1,3)
    FOLD(2,0) FOLD(2,1) FOLD(2,2) FOLD(2,3)
    FOLD(3,0) FOLD(3,1) FOLD(3,2) FOLD(3,3)
    a00=Z;a01=Z;a02=Z;a03=Z; a10=Z;a11=Z;a12=Z;a13=Z;
    a20=Z;a21=Z;a22=Z;a23=Z; a30=Z;a31=Z;a32=Z;a33=Z;
  }

  // cross-lane (fr) merge, then cross-wave merge via LDS
  MERGE(0,0) MERGE(0,1) MERGE(0,2) MERGE(0,3)
  MERGE(1,0) MERGE(1,1) MERGE(1,2) MERGE(1,3)
  MERGE(2,0) MERGE(2,1) MERGE(2,2) MERGE(2,3)
  MERGE(3,0) MERGE(3,1) MERGE(3,2) MERGE(3,3)
  __syncthreads();
  if (tid < 64){
    float4 p = comb[tid][0];
    float v1 = p.x, v2 = p.z;
    int   i1 = __float_as_int(p.y);
    #pragma unroll
    for (int w = 1; w < 4; ++w){
      p = comb[tid][w];
      bool tk = p.x < v1;
      v2 = tk ? fminf(v1, p.z) : fminf(v2, p.x);
      i1 = tk ? __float_as_int(p.y) : i1;
      v1 = tk ? p.x : v1;
    }
    const int r = n0 + tid;
    idx[r]  = i1;
    out2[r] = (float)i1;
    bool flg = !(v2 - v1 >= THETA);
    if (flg){
      unsigned pos = atomicAdd(cnt, 1u);
      wl[pos] = (unsigned)r;
    }
    // fused loss: d(r, i1) = sx[r] + v1 for unflagged rows (refine adds flagged rows)
    double c = flg ? 0.0 : (double)(sx[r] + v1);
    #pragma unroll
    for (int m = 1; m < 64; m <<= 1) c += __shfl_xor(c, m);
    if (tid == 0) atomicAdd(accd, c);
  }
}

// ---- kernel 3: exact fp32-numpy-emulated full re-scan of flagged rows (8 rows/block) ----
__global__ __launch_bounds__(256) void vq_refine(
    const float* __restrict__ x, const float* __restrict__ cb,
    const float* __restrict__ sx, const float* __restrict__ se,
    const unsigned* __restrict__ wl, const unsigned* __restrict__ cnt,
    int* __restrict__ idx, float* __restrict__ out2, double* __restrict__ accd)
{
  __shared__ float eT[8][1024];   // 32 KiB transposed codebook chunk
  __shared__ float xs[DIMS][8];   // 8 KiB
  __shared__ int   rows_s[8];
  __shared__ float sxs[8];
  __shared__ float wv[4][8];
  __shared__ int   wi[4][8];

  const unsigned n = *cnt;
  const unsigned groups = (n + 7u) >> 3;
  const int tid  = threadIdx.x;
  const int lane = tid & 63;
  const int wid  = tid >> 6;

  for (unsigned g = blockIdx.x; g < groups; g += gridDim.x){
    __syncthreads();   // protect rows_s/xs/wv reuse across groups
    if (tid < 8){
      unsigned e = g*8u + (unsigned)tid;
      int row = (int)wl[e < n ? e : (n - 1u)];
      rows_s[tid] = row;
      sxs[tid] = sx[row];
    }
    __syncthreads();
    // stage x rows (scattered gather along c)
    #pragma unroll
    for (int rep = 0; rep < 8; ++rep){
      int id = rep * 256 + tid;
      int c = id >> 3, r = id & 7;
      int row = rows_s[r];
      int b = row >> 12, t = row & 4095;
      xs[c][r] = x[((size_t)(b*DIMS + c))*NT + t];
    }

    float s[8][4];
    #pragma unroll
    for (int r = 0; r < 8; ++r)
      #pragma unroll
      for (int u = 0; u < 4; ++u) s[r][u] = 0.f;

    for (int c0 = 0; c0 < DIMS; c0 += 8){
      __syncthreads();
      #pragma unroll
      for (int rep = 0; rep < 8; ++rep){
        int id2 = rep * 256 + tid;
        int k = id2 >> 1, q = id2 & 1;
        float4 v = *(const float4*)&cb[(size_t)k * DIMS + c0 + q * 4];
        eT[q*4 + 0][k] = v.x; eT[q*4 + 1][k] = v.y;
        eT[q*4 + 2][k] = v.z; eT[q*4 + 3][k] = v.w;
      }
      __syncthreads();
      #pragma unroll
      for (int cc = 0; cc < 8; ++cc){
        float4 ev = *(const float4*)&eT[cc][wid*256 + lane*4];
        #pragma unroll
        for (int r = 0; r < 8; ++r){
          float xv = xs[c0 + cc][r];
          s[r][0] = fmaf(xv, ev.x, s[r][0]);
          s[r][1] = fmaf(xv, ev.y, s[r][1]);
          s[r][2] = fmaf(xv, ev.z, s[r][2]);
          s[r][3] = fmaf(xv, ev.w, s[r][3]);
        }
      }
    }

    float4 sek = *(const float4*)&se[wid*256 + lane*4];
    #pragma unroll
    for (int r = 0; r < 8; ++r){
      const float sxv = sxs[r];
      float bv = 3.4e38f; int bi = 0x7fffffff;
      #pragma unroll
      for (int u = 0; u < 4; ++u){
        float d = __fsub_rn(__fadd_rn(sxv, (&sek.x)[u]),
                            __fadd_rn(s[r][u], s[r][u]));
        int k = wid*256 + lane*4 + u;
        if (d < bv || (d == bv && k < bi)) { bv = d; bi = k; }
      }
      #pragma unroll
      for (int m = 1; m < 64; m <<= 1){
        float ov = __shfl_xor(bv, m);
        int   oi = __shfl_xor(bi, m);
        if (ov < bv || (ov == bv && oi < bi)) { bv = ov; bi = oi; }
      }
      if (lane == 0){ wv[wid][r] = bv; wi[wid][r] = bi; }
    }
    __syncthreads();
    if (tid < 8){
      const int r = tid;
      float bv = wv[0][r]; int bi = wi[0][r];
      #pragma unroll
      for (int w = 1; w < 4; ++w){
        float ov = wv[w][r]; int oi = wi[w][r];
        if (ov < bv || (ov == bv && oi < bi)) { bv = ov; bi = oi; }
      }
      if (g*8u + (unsigned)r < n){
        int row = rows_s[r];
        idx[row]  = bi;
        out2[row] = (float)bi;
        atomicAdd(accd, (double)bv);   // exact loss contribution for flagged row
      }
    }
  }
}

// ---- kernel 4: scatter quantized = cb[idx] (no x read, loss already accumulated) ----
__global__ __launch_bounds__(256) void vq_scatter(
    const float* __restrict__ cb, const int* __restrict__ idx, float* __restrict__ out0)
{
  __shared__ float col[1024];
  const int bc = blockIdx.x;          // b*256 + c
  const int bb = bc >> 8;
  const int c  = bc & 255;
  #pragma unroll
  for (int kk = 0; kk < 4; ++kk)
    col[kk*256 + threadIdx.x] = cb[(size_t)(kk*256 + threadIdx.x) * DIMS + c];
  __syncthreads();

  float* orow = out0 + (size_t)bc * NT;
  const int* ir = idx + bb * NT;
  #pragma unroll
  for (int j = 0; j < 4; ++j){
    const int t = (threadIdx.x << 2) + (j << 10);
    int4  iv  = *(const int4*)(ir + t);
    float4 q;
    q.x = col[iv.x];
    q.y = col[iv.y];
    q.z = col[iv.z];
    q.w = col[iv.w];
    *(float4*)(orow + t) = q;
  }
}

__global__ void vq_final(const double* __restrict__ accd, float* __restrict__ out1){
  *out1 = (float)(1.25 * (*accd) * (1.0 / 16777216.0));
}

extern "C" void kernel_launch(void* const* d_in, const int* in_sizes, int n_in,
                              void* d_out, int out_size, void* d_ws, size_t ws_size,
                              hipStream_t stream)
{
  const float* x  = (const float*)d_in[0];
  const float* cb = (const float*)d_in[1];
  float* out  = (float*)d_out;
  float* out0 = out;
  float* out1 = out + (size_t)16777216;   // vq_loss
  float* out2 = out + (size_t)16777217;   // indices as float [65536]

  char* ws = (char*)d_ws;
  double*   accd = (double*)(ws + 0);
  unsigned* cnt  = (unsigned*)(ws + 8);
  float*    se   = (float*)(ws + 64);       // 4 KiB
  float*    sx   = (float*)(ws + 4160);     // 256 KiB
  int*      idx  = (int*)(ws + 266304);     // 256 KiB
  _Float16* cb16 = (_Float16*)(ws + 528448);// 512 KiB fp16 codebook (x512)

  // worklist lives in the out0 region (consumed by refine before scatter overwrites):
  unsigned* wl = (unsigned*)(out + (size_t)4*1024*1024);   // at 16 MiB, 256 KiB

  hipMemsetAsync(d_ws, 0, 16, stream);     // zero loss accumulator + worklist count
  vq_sx     <<<dim3(256),  dim3(256), 0, stream>>>(x, sx);
  vq_se     <<<dim3(16),   dim3(64),  0, stream>>>(cb, se);
  vq_cvt    <<<dim3(256),  dim3(256), 0, stream>>>(cb, cb16);
  vq_scores <<<dim3(1024), dim3(256), 0, stream>>>(x, cb16, se, sx, idx, out2, wl, cnt, accd);
  vq_refine <<<dim3(512),  dim3(256), 0, stream>>>(x, cb, sx, se, wl, cnt, idx, out2, accd);
  vq_scatter<<<dim3(4096), dim3(256), 0, stream>>>(cb, idx, out0);
  vq_final  <<<dim3(1),    dim3(1),   0, stream>>>(accd, out1);
}

// Round 10
// 222.285 us; speedup vs baseline: 1.2851x; 1.0528x over previous
//
#include <hip/hip_runtime.h>
#include <stdint.h>

#define DIMS 256
#define NT 4096
#define NROWS 65536
#define THETA 1.5e-4f

typedef float    f32x4_t __attribute__((ext_vector_type(4)));
typedef _Float16 f16x8_t __attribute__((ext_vector_type(8)));
typedef _Float16 f16x4_t __attribute__((ext_vector_type(4)));

// ---- kernel 0a: sx[n] = np.sum(flat*flat, axis=1) bit-exact, 16 threads/row ----
// thread (h,j) owns pairwise accumulator r[j] of half h; exact combine tree via shfl_xor.
__global__ __launch_bounds__(256) void vq_sx(const float* __restrict__ x, float* __restrict__ sx){
  const int tid = threadIdx.x;
  const int r16 = tid >> 4;          // row within block (0..15)
  const int hj  = tid & 15;
  const int h   = hj >> 3, j = hj & 7;
  const int n   = blockIdx.x * 16 + r16;
  const int b   = n >> 12, t = n & 4095;
  const float* xp = x + ((size_t)(b*DIMS + h*128 + j)) * NT + t;
  float v0 = xp[0];
  float r = __fmul_rn(v0, v0);
  #pragma unroll
  for (int i = 1; i < 16; ++i){
    float v = xp[(size_t)i * 8 * NT];
    r = __fadd_rn(r, __fmul_rn(v, v));
  }
  // (((r0+r1)+(r2+r3))+((r4+r5)+(r6+r7))) then half0+half1 — commutative-safe xor tree
  r = __fadd_rn(r, __shfl_xor(r, 1));
  r = __fadd_rn(r, __shfl_xor(r, 2));
  r = __fadd_rn(r, __shfl_xor(r, 4));
  r = __fadd_rn(r, __shfl_xor(r, 8));
  if (hj == 0) sx[n] = r;
}

// ---- kernel 0b: se[k] = np.sum(cb*cb, axis=1) bit-exact ----
__global__ void vq_se(const float* __restrict__ cb, float* __restrict__ se){
  const int k = blockIdx.x * 64 + threadIdx.x;
  const float* ep = cb + (size_t)k * DIMS;
  float half[2];
  #pragma unroll
  for (int h = 0; h < 2; ++h){
    float r[8];
    #pragma unroll
    for (int j = 0; j < 8; ++j){
      float v = ep[h*128 + j];
      r[j] = __fmul_rn(v, v);
    }
    for (int i = 8; i < 128; i += 8){
      #pragma unroll
      for (int j = 0; j < 8; ++j){
        float v = ep[h*128 + i + j];
        r[j] = __fadd_rn(r[j], __fmul_rn(v, v));
      }
    }
    half[h] = __fadd_rn(__fadd_rn(__fadd_rn(r[0], r[1]), __fadd_rn(r[2], r[3])),
                        __fadd_rn(__fadd_rn(r[4], r[5]), __fadd_rn(r[6], r[7])));
  }
  se[k] = __fadd_rn(half[0], half[1]);
}

// ---- kernel 0c: cb16[k][c] = (_Float16)(cb[k][c] * 512) once (pure-pow2 scale) ----
__global__ __launch_bounds__(256) void vq_cvt(const float* __restrict__ cb, _Float16* __restrict__ cb16){
  const int i = (blockIdx.x * 256 + threadIdx.x) * 4;
  float4 v = *(const float4*)(cb + i);
  f16x4_t p;
  p.x = (_Float16)(v.x * 512.f);
  p.y = (_Float16)(v.y * 512.f);
  p.z = (_Float16)(v.z * 512.f);
  p.w = (_Float16)(v.w * 512.f);
  *(f16x4_t*)(cb16 + i) = p;
}

// ================= kernel 1: approx scores, 8 waves, LDS B double-buffer =================
// 64 rows/block x 1024 codes; waves: wr = row-half (32 rows, M=2), wc = 64-code stripe.
// score v = se_k - 2*dot; loss fused (unflagged rows: sx[r] + v1).

#define T2I(v, i, v1, i1, v2) { \
  bool lt = (v) < (v1); \
  (v2) = lt ? (v1) : fminf((v2), (v)); \
  (i1) = lt ? (i) : (i1); \
  (v1) = lt ? (v) : (v1); }

#define DECL_T2(M,R) \
  float b1_##M##R = 3.4e38f, b2_##M##R = 3.4e38f; int bi_##M##R = 0x7fffffff;

#define FOLD(M,R) { \
  float v; \
  v = fmaf(a##M##0[R], NEGI, ec0); T2I(v, kc0, b1_##M##R, bi_##M##R, b2_##M##R); \
  v = fmaf(a##M##1[R], NEGI, ec1); T2I(v, kc1, b1_##M##R, bi_##M##R, b2_##M##R); \
  v = fmaf(a##M##2[R], NEGI, ec2); T2I(v, kc2, b1_##M##R, bi_##M##R, b2_##M##R); \
  v = fmaf(a##M##3[R], NEGI, ec3); T2I(v, kc3, b1_##M##R, bi_##M##R, b2_##M##R); }

#define BSTEP(CC) { \
  *(f16x8_t*)&Bh[(CC)&1][codeS][cOff]     = rb0; \
  *(f16x8_t*)&Bh[(CC)&1][codeS][cOff + 8] = rb1; \
  if ((CC) < 7){ \
    const _Float16* p_ = bsrcKt + ((CC)+1)*32; \
    rb0 = *(const f16x8_t*)(p_); rb1 = *(const f16x8_t*)(p_ + 8); \
  } else if (kt < 3){ \
    const _Float16* p_ = bsrcKt + 256*DIMS; \
    rb0 = *(const f16x8_t*)(p_); rb1 = *(const f16x8_t*)(p_ + 8); \
  } \
  __syncthreads(); \
  { \
    f16x8_t bh0 = *(const f16x8_t*)&Bh[(CC)&1][bC0][fq8]; \
    f16x8_t bh1 = *(const f16x8_t*)&Bh[(CC)&1][bC1][fq8]; \
    f16x8_t bh2 = *(const f16x8_t*)&Bh[(CC)&1][bC2][fq8]; \
    f16x8_t bh3 = *(const f16x8_t*)&Bh[(CC)&1][bC3][fq8]; \
    f16x8_t ah0 = *(const f16x8_t*)&Ah[wr32 + fr][(CC)*32 + fq8]; \
    f16x8_t ah1 = *(const f16x8_t*)&Ah[wr32 + 16 + fr][(CC)*32 + fq8]; \
    a00 = __builtin_amdgcn_mfma_f32_16x16x32_f16(ah0, bh0, a00, 0, 0, 0); \
    a01 = __builtin_amdgcn_mfma_f32_16x16x32_f16(ah0, bh1, a01, 0, 0, 0); \
    a02 = __builtin_amdgcn_mfma_f32_16x16x32_f16(ah0, bh2, a02, 0, 0, 0); \
    a03 = __builtin_amdgcn_mfma_f32_16x16x32_f16(ah0, bh3, a03, 0, 0, 0); \
    a10 = __builtin_amdgcn_mfma_f32_16x16x32_f16(ah1, bh0, a10, 0, 0, 0); \
    a11 = __builtin_amdgcn_mfma_f32_16x16x32_f16(ah1, bh1, a11, 0, 0, 0); \
    a12 = __builtin_amdgcn_mfma_f32_16x16x32_f16(ah1, bh2, a12, 0, 0, 0); \
    a13 = __builtin_amdgcn_mfma_f32_16x16x32_f16(ah1, bh3, a13, 0, 0, 0); \
  } }

#define MSTEP(MK) { \
  float ov1 = __shfl_xor(v1, MK); int oi1 = __shfl_xor(i1, MK); float ov2 = __shfl_xor(v2, MK); \
  bool tk = ov1 < v1; \
  v2 = tk ? fminf(v1, ov2) : fminf(v2, ov1); \
  i1 = tk ? oi1 : i1; \
  v1 = tk ? ov1 : v1; }

#define MERGE(M,R) { \
  float v1 = b1_##M##R, v2 = b2_##M##R; int i1 = bi_##M##R; \
  MSTEP(1) MSTEP(2) MSTEP(4) MSTEP(8) \
  if (fr == 0) comb[wr32 + (M)*16 + fq*4 + (R)][wc] = make_float4(v1, __int_as_float(i1), v2, 0.f); }

__global__ __launch_bounds__(512, 1) void vq_scores(
    const float* __restrict__ x, const _Float16* __restrict__ cb16,
    const float* __restrict__ se, const float* __restrict__ sx,
    int* __restrict__ idx, float* __restrict__ out2,
    unsigned* __restrict__ wl, unsigned* __restrict__ cnt, double* __restrict__ accd)
{
  __shared__ _Float16 Ah[64][264];        // 33792 B, row stride 132 dw === 4 (mod 32)
  __shared__ _Float16 Bh[2][256][40];     // 40960 B
  __shared__ float4   comb[64][4];        //  4096 B  -> total 78848 B, 2 blocks/CU

  const int tid  = threadIdx.x;
  const int lane = tid & 63;
  const int wid  = tid >> 6;
  const int wr   = wid >> 2;              // row half (32 rows)
  const int wc   = wid & 3;               // 64-code stripe within 256-code kt tile
  const int fr   = lane & 15;
  const int fq   = lane >> 4;
  const int wr32 = wr * 32;
  const int fq8  = fq * 8;
  const int n0   = blockIdx.x * 64;
  const int bb   = n0 >> 12;
  const int t0   = n0 & 4095;
  const float NEGI = -1.0f/256.0f;

  // B staging: thread -> (codeS = tid>>1, cOff = (tid&1)*16 halves); 32B per thread per step
  const int codeS = tid >> 1;
  const int cOff  = (tid & 1) << 4;

  f16x8_t rb0, rb1;
  {
    const _Float16* p_ = cb16 + (size_t)codeS * DIMS + cOff;   // kt=0, cc=0
    rb0 = *(const f16x8_t*)(p_); rb1 = *(const f16x8_t*)(p_ + 8);
  }

  // ---- stage A once: 64 rows x 256 c, fp16 (512 threads) ----
  {
    const int dup = tid >> 7;                 // 0..3
    const int c4  = tid & 7;                  // c quad within chunk
    const int tt  = ((tid >> 3) & 15) << 2;   // 4-row group
    #pragma unroll
    for (int cc2 = 0; cc2 < 2; ++cc2){
      const int c0 = (dup*2 + cc2) * 32;
      const float* xp = x + ((size_t)(bb*DIMS + c0 + c4*4))*NT + t0 + tt;
      float4 va0 = *(const float4*)(xp);
      float4 va1 = *(const float4*)(xp + NT);
      float4 va2 = *(const float4*)(xp + 2*NT);
      float4 va3 = *(const float4*)(xp + 3*NT);
      #pragma unroll
      for (int j = 0; j < 4; ++j){
        f16x4_t p;
        p.x = (_Float16)((&va0.x)[j]);
        p.y = (_Float16)((&va1.x)[j]);
        p.z = (_Float16)((&va2.x)[j]);
        p.w = (_Float16)((&va3.x)[j]);
        *(f16x4_t*)&Ah[tt + j][c0 + c4*4] = p;
      }
    }
  }
  if (tid < 256)
    comb[tid >> 2][tid & 3] = make_float4(3.4e38f, __int_as_float(0x7fffffff), 3.4e38f, 0.f);

  // named accumulators (8 x f32x4) + top-2 state (8 rows/thread)
  const f32x4_t Z = {0.f, 0.f, 0.f, 0.f};
  f32x4_t a00=Z,a01=Z,a02=Z,a03=Z, a10=Z,a11=Z,a12=Z,a13=Z;
  DECL_T2(0,0) DECL_T2(0,1) DECL_T2(0,2) DECL_T2(0,3)
  DECL_T2(1,0) DECL_T2(1,1) DECL_T2(1,2) DECL_T2(1,3)

  const int bC0 = wc*64 + 0*16 + fr;
  const int bC1 = wc*64 + 1*16 + fr;
  const int bC2 = wc*64 + 2*16 + fr;
  const int bC3 = wc*64 + 3*16 + fr;

  for (int kt = 0; kt < 4; ++kt){
    const _Float16* bsrcKt = cb16 + ((size_t)(kt*256) + codeS) * DIMS + cOff;
    BSTEP(0) BSTEP(1) BSTEP(2) BSTEP(3)
    BSTEP(4) BSTEP(5) BSTEP(6) BSTEP(7)

    // fold this kt's 64 codes into the running top-2 (all named scalars)
    const int kb  = kt*256 + wc*64 + fr;
    const int kc0 = kb, kc1 = kb + 16, kc2 = kb + 32, kc3 = kb + 48;
    const float ec0 = se[kc0], ec1 = se[kc1], ec2 = se[kc2], ec3 = se[kc3];
    FOLD(0,0) FOLD(0,1) FOLD(0,2) FOLD(0,3)
    FOLD(1,0) FOLD(1,1) FOLD(1,2) FOLD(1,3)
    a00=Z;a01=Z;a02=Z;a03=Z; a10=Z;a11=Z;a12=Z;a13=Z;
  }

  // cross-lane (fr) merge, then cross-wave merge via LDS
  MERGE(0,0) MERGE(0,1) MERGE(0,2) MERGE(0,3)
  MERGE(1,0) MERGE(1,1) MERGE(1,2) MERGE(1,3)
  __syncthreads();
  if (tid < 64){
    float4 p = comb[tid][0];
    float v1 = p.x, v2 = p.z;
    int   i1 = __float_as_int(p.y);
    #pragma unroll
    for (int w = 1; w < 4; ++w){
      p = comb[tid][w];
      bool tk = p.x < v1;
      v2 = tk ? fminf(v1, p.z) : fminf(v2, p.x);
      i1 = tk ? __float_as_int(p.y) : i1;
      v1 = tk ? p.x : v1;
    }
    const int r = n0 + tid;
    idx[r]  = i1;
    out2[r] = (float)i1;
    bool flg = !(v2 - v1 >= THETA);
    if (flg){
      unsigned pos = atomicAdd(cnt, 1u);
      wl[pos] = (unsigned)r;
    }
    // fused loss: d(r, i1) = sx[r] + v1 for unflagged rows (refine adds flagged rows)
    double c = flg ? 0.0 : (double)(sx[r] + v1);
    #pragma unroll
    for (int m = 1; m < 64; m <<= 1) c += __shfl_xor(c, m);
    if (tid == 0) atomicAdd(accd, c);
  }
}

// ---- kernel 3: exact fp32-numpy-emulated full re-scan of flagged rows (8 rows/block) ----
__global__ __launch_bounds__(256) void vq_refine(
    const float* __restrict__ x, const float* __restrict__ cb,
    const float* __restrict__ sx, const float* __restrict__ se,
    const unsigned* __restrict__ wl, const unsigned* __restrict__ cnt,
    int* __restrict__ idx, float* __restrict__ out2, double* __restrict__ accd)
{
  __shared__ float eT[8][1024];   // 32 KiB transposed codebook chunk
  __shared__ float xs[DIMS][8];   // 8 KiB
  __shared__ int   rows_s[8];
  __shared__ float sxs[8];
  __shared__ float wv[4][8];
  __shared__ int   wi[4][8];

  const unsigned n = *cnt;
  const unsigned groups = (n + 7u) >> 3;
  const int tid  = threadIdx.x;
  const int lane = tid & 63;
  const int wid  = tid >> 6;

  for (unsigned g = blockIdx.x; g < groups; g += gridDim.x){
    __syncthreads();   // protect rows_s/xs/wv reuse across groups
    if (tid < 8){
      unsigned e = g*8u + (unsigned)tid;
      int row = (int)wl[e < n ? e : (n - 1u)];
      rows_s[tid] = row;
      sxs[tid] = sx[row];
    }
    __syncthreads();
    // stage x rows (scattered gather along c)
    #pragma unroll
    for (int rep = 0; rep < 8; ++rep){
      int id = rep * 256 + tid;
      int c = id >> 3, r = id & 7;
      int row = rows_s[r];
      int b = row >> 12, t = row & 4095;
      xs[c][r] = x[((size_t)(b*DIMS + c))*NT + t];
    }

    float s[8][4];
    #pragma unroll
    for (int r = 0; r < 8; ++r)
      #pragma unroll
      for (int u = 0; u < 4; ++u) s[r][u] = 0.f;

    for (int c0 = 0; c0 < DIMS; c0 += 8){
      __syncthreads();
      #pragma unroll
      for (int rep = 0; rep < 8; ++rep){
        int id2 = rep * 256 + tid;
        int k = id2 >> 1, q = id2 & 1;
        float4 v = *(const float4*)&cb[(size_t)k * DIMS + c0 + q * 4];
        eT[q*4 + 0][k] = v.x; eT[q*4 + 1][k] = v.y;
        eT[q*4 + 2][k] = v.z; eT[q*4 + 3][k] = v.w;
      }
      __syncthreads();
      #pragma unroll
      for (int cc = 0; cc < 8; ++cc){
        float4 ev = *(const float4*)&eT[cc][wid*256 + lane*4];
        #pragma unroll
        for (int r = 0; r < 8; ++r){
          float xv = xs[c0 + cc][r];
          s[r][0] = fmaf(xv, ev.x, s[r][0]);
          s[r][1] = fmaf(xv, ev.y, s[r][1]);
          s[r][2] = fmaf(xv, ev.z, s[r][2]);
          s[r][3] = fmaf(xv, ev.w, s[r][3]);
        }
      }
    }

    float4 sek = *(const float4*)&se[wid*256 + lane*4];
    #pragma unroll
    for (int r = 0; r < 8; ++r){
      const float sxv = sxs[r];
      float bv = 3.4e38f; int bi = 0x7fffffff;
      #pragma unroll
      for (int u = 0; u < 4; ++u){
        float d = __fsub_rn(__fadd_rn(sxv, (&sek.x)[u]),
                            __fadd_rn(s[r][u], s[r][u]));
        int k = wid*256 + lane*4 + u;
        if (d < bv || (d == bv && k < bi)) { bv = d; bi = k; }
      }
      #pragma unroll
      for (int m = 1; m < 64; m <<= 1){
        float ov = __shfl_xor(bv, m);
        int   oi = __shfl_xor(bi, m);
        if (ov < bv || (ov == bv && oi < bi)) { bv = ov; bi = oi; }
      }
      if (lane == 0){ wv[wid][r] = bv; wi[wid][r] = bi; }
    }
    __syncthreads();
    if (tid < 8){
      const int r = tid;
      float bv = wv[0][r]; int bi = wi[0][r];
      #pragma unroll
      for (int w = 1; w < 4; ++w){
        float ov = wv[w][r]; int oi = wi[w][r];
        if (ov < bv || (ov == bv && oi < bi)) { bv = ov; bi = oi; }
      }
      if (g*8u + (unsigned)r < n){
        int row = rows_s[r];
        idx[row]  = bi;
        out2[row] = (float)bi;
        atomicAdd(accd, (double)bv);   // exact loss contribution for flagged row
      }
    }
  }
}

// ---- kernel 4: scatter quantized = cb[idx] (no x read, loss already accumulated) ----
__global__ __launch_bounds__(256) void vq_scatter(
    const float* __restrict__ cb, const int* __restrict__ idx, float* __restrict__ out0)
{
  __shared__ float col[1024];
  const int bc = blockIdx.x;          // b*256 + c
  const int bb = bc >> 8;
  const int c  = bc & 255;
  #pragma unroll
  for (int kk = 0; kk < 4; ++kk)
    col[kk*256 + threadIdx.x] = cb[(size_t)(kk*256 + threadIdx.x) * DIMS + c];
  __syncthreads();

  float* orow = out0 + (size_t)bc * NT;
  const int* ir = idx + bb * NT;
  #pragma unroll
  for (int j = 0; j < 4; ++j){
    const int t = (threadIdx.x << 2) + (j << 10);
    int4  iv  = *(const int4*)(ir + t);
    float4 q;
    q.x = col[iv.x];
    q.y = col[iv.y];
    q.z = col[iv.z];
    q.w = col[iv.w];
    *(float4*)(orow + t) = q;
  }
}

__global__ void vq_final(const double* __restrict__ accd, float* __restrict__ out1){
  *out1 = (float)(1.25 * (*accd) * (1.0 / 16777216.0));
}

extern "C" void kernel_launch(void* const* d_in, const int* in_sizes, int n_in,
                              void* d_out, int out_size, void* d_ws, size_t ws_size,
                              hipStream_t stream)
{
  const float* x  = (const float*)d_in[0];
  const float* cb = (const float*)d_in[1];
  float* out  = (float*)d_out;
  float* out0 = out;
  float* out1 = out + (size_t)16777216;   // vq_loss
  float* out2 = out + (size_t)16777217;   // indices as float [65536]

  char* ws = (char*)d_ws;
  double*   accd = (double*)(ws + 0);
  unsigned* cnt  = (unsigned*)(ws + 8);
  float*    se   = (float*)(ws + 64);       // 4 KiB
  float*    sx   = (float*)(ws + 4160);     // 256 KiB
  int*      idx  = (int*)(ws + 266304);     // 256 KiB
  _Float16* cb16 = (_Float16*)(ws + 528448);// 512 KiB fp16 codebook (x512)

  // worklist lives in the out0 region (consumed by refine before scatter overwrites):
  unsigned* wl = (unsigned*)(out + (size_t)4*1024*1024);   // at 16 MiB, 256 KiB

  hipMemsetAsync(d_ws, 0, 16, stream);     // zero loss accumulator + worklist count
  vq_sx     <<<dim3(4096), dim3(256), 0, stream>>>(x, sx);
  vq_se     <<<dim3(16),   dim3(64),  0, stream>>>(cb, se);
  vq_cvt    <<<dim3(256),  dim3(256), 0, stream>>>(cb, cb16);
  vq_scores <<<dim3(1024), dim3(512), 0, stream>>>(x, cb16, se, sx, idx, out2, wl, cnt, accd);
  vq_refine <<<dim3(512),  dim3(256), 0, stream>>>(x, cb, sx, se, wl, cnt, idx, out2, accd);
  vq_scatter<<<dim3(4096), dim3(256), 0, stream>>>(cb, idx, out0);
  vq_final  <<<dim3(1),    dim3(1),   0, stream>>>(accd, out1);
}

// Round 11
// 172.221 us; speedup vs baseline: 1.6587x; 1.2907x over previous
//
#include <hip/hip_runtime.h>
#include <stdint.h>

#define DIMS 256
#define NT 4096
#define NROWS 65536
#define THETA 1.5e-4f

typedef float    f32x4_t __attribute__((ext_vector_type(4)));
typedef _Float16 f16x8_t __attribute__((ext_vector_type(8)));
typedef _Float16 f16x4_t __attribute__((ext_vector_type(4)));

// ---- kernel 0: fused se (bit-exact numpy pairwise) + cb16 = fp16(cb*512) ----
__global__ __launch_bounds__(64) void vq_prep(const float* __restrict__ cb,
                                              float* __restrict__ se,
                                              _Float16* __restrict__ cb16){
  __shared__ float sq[256];
  const int k = blockIdx.x;
  const int tid = threadIdx.x;
  float4 v = *(const float4*)(cb + (size_t)k*256 + tid*4);
  f16x4_t p;
  p.x = (_Float16)(v.x * 512.f);
  p.y = (_Float16)(v.y * 512.f);
  p.z = (_Float16)(v.z * 512.f);
  p.w = (_Float16)(v.w * 512.f);
  *(f16x4_t*)(cb16 + (size_t)k*256 + tid*4) = p;
  sq[tid*4+0] = __fmul_rn(v.x, v.x);
  sq[tid*4+1] = __fmul_rn(v.y, v.y);
  sq[tid*4+2] = __fmul_rn(v.z, v.z);
  sq[tid*4+3] = __fmul_rn(v.w, v.w);
  __syncthreads();
  if (tid < 16){
    const int h = tid >> 3, j = tid & 7;
    float r = sq[h*128 + j];
    #pragma unroll
    for (int i = 1; i < 16; ++i) r = __fadd_rn(r, sq[h*128 + j + 8*i]);
    r = __fadd_rn(r, __shfl_xor(r, 1));
    r = __fadd_rn(r, __shfl_xor(r, 2));
    r = __fadd_rn(r, __shfl_xor(r, 4));
    r = __fadd_rn(r, __shfl_xor(r, 8));
    if (tid == 0) se[k] = r;
  }
}

// ================= kernel 1: scores + fused loss + fused output write =================
// 64 rows/block x 1024 codes; 8 waves: wr = row-half (M=2), wc = 64-code stripe.
// score v = se_k - 2*dot (fp16 MFMA approx); flagged rows -> refine.
// Epilogue: stage 64 selected cb rows (fp32) in LDS union, write out0 tile coalesced.

#define AH(r,c)    Ah[(size_t)(r)*264 + (c)]
#define BHL(s,k,c) Bh[((size_t)((s)*256 + (k)))*40 + (c)]
#define QQ(t,c)    q[(size_t)(t)*260 + (c)]

#define T2I(v, i, v1, i1, v2) { \
  bool lt = (v) < (v1); \
  (v2) = lt ? (v1) : fminf((v2), (v)); \
  (i1) = lt ? (i) : (i1); \
  (v1) = lt ? (v) : (v1); }

#define DECL_T2(M,R) \
  float b1_##M##R = 3.4e38f, b2_##M##R = 3.4e38f; int bi_##M##R = 0x7fffffff;

#define FOLD(M,R) { \
  float v; \
  v = fmaf(a##M##0[R], NEGI, ec0); T2I(v, kc0, b1_##M##R, bi_##M##R, b2_##M##R); \
  v = fmaf(a##M##1[R], NEGI, ec1); T2I(v, kc1, b1_##M##R, bi_##M##R, b2_##M##R); \
  v = fmaf(a##M##2[R], NEGI, ec2); T2I(v, kc2, b1_##M##R, bi_##M##R, b2_##M##R); \
  v = fmaf(a##M##3[R], NEGI, ec3); T2I(v, kc3, b1_##M##R, bi_##M##R, b2_##M##R); }

#define BSTEP(CC) { \
  *(f16x8_t*)&BHL((CC)&1, codeS, cOff)     = rb0; \
  *(f16x8_t*)&BHL((CC)&1, codeS, cOff + 8) = rb1; \
  if ((CC) < 7){ \
    const _Float16* p_ = bsrcKt + ((CC)+1)*32; \
    rb0 = *(const f16x8_t*)(p_); rb1 = *(const f16x8_t*)(p_ + 8); \
  } else if (kt < 3){ \
    const _Float16* p_ = bsrcKt + 256*DIMS; \
    rb0 = *(const f16x8_t*)(p_); rb1 = *(const f16x8_t*)(p_ + 8); \
  } \
  __syncthreads(); \
  { \
    f16x8_t bh0 = *(const f16x8_t*)&BHL((CC)&1, bC0, fq8); \
    f16x8_t bh1 = *(const f16x8_t*)&BHL((CC)&1, bC1, fq8); \
    f16x8_t bh2 = *(const f16x8_t*)&BHL((CC)&1, bC2, fq8); \
    f16x8_t bh3 = *(const f16x8_t*)&BHL((CC)&1, bC3, fq8); \
    f16x8_t ah0 = *(const f16x8_t*)&AH(wr32 + fr, (CC)*32 + fq8); \
    f16x8_t ah1 = *(const f16x8_t*)&AH(wr32 + 16 + fr, (CC)*32 + fq8); \
    a00 = __builtin_amdgcn_mfma_f32_16x16x32_f16(ah0, bh0, a00, 0, 0, 0); \
    a01 = __builtin_amdgcn_mfma_f32_16x16x32_f16(ah0, bh1, a01, 0, 0, 0); \
    a02 = __builtin_amdgcn_mfma_f32_16x16x32_f16(ah0, bh2, a02, 0, 0, 0); \
    a03 = __builtin_amdgcn_mfma_f32_16x16x32_f16(ah0, bh3, a03, 0, 0, 0); \
    a10 = __builtin_amdgcn_mfma_f32_16x16x32_f16(ah1, bh0, a10, 0, 0, 0); \
    a11 = __builtin_amdgcn_mfma_f32_16x16x32_f16(ah1, bh1, a11, 0, 0, 0); \
    a12 = __builtin_amdgcn_mfma_f32_16x16x32_f16(ah1, bh2, a12, 0, 0, 0); \
    a13 = __builtin_amdgcn_mfma_f32_16x16x32_f16(ah1, bh3, a13, 0, 0, 0); \
  } }

#define MSTEP(MK) { \
  float ov1 = __shfl_xor(v1, MK); int oi1 = __shfl_xor(i1, MK); float ov2 = __shfl_xor(v2, MK); \
  bool tk = ov1 < v1; \
  v2 = tk ? fminf(v1, ov2) : fminf(v2, ov1); \
  i1 = tk ? oi1 : i1; \
  v1 = tk ? ov1 : v1; }

#define MERGE(M,R) { \
  float v1 = b1_##M##R, v2 = b2_##M##R; int i1 = bi_##M##R; \
  MSTEP(1) MSTEP(2) MSTEP(4) MSTEP(8) \
  if (fr == 0) comb[(wr32 + (M)*16 + fq*4 + (R))*4 + wc] = make_float4(v1, __int_as_float(i1), v2, 0.f); }

__global__ __launch_bounds__(512, 1) void vq_scores(
    const float* __restrict__ x, const float* __restrict__ cb,
    const _Float16* __restrict__ cb16, const float* __restrict__ se,
    float* __restrict__ out0, float* __restrict__ out2,
    unsigned* __restrict__ wl, unsigned* __restrict__ cnt, double* __restrict__ accd)
{
  // smem layout: Ah [64][264] f16 @0 (33792B); Bh [2][256][40] f16 @33792 (40960B);
  // comb [64][4] float4 @74752 (4096B); codeL [64] int @78848; sxa [64] f32 @79104.
  // q [64][260] f32 (66560B) aliases Ah+Bh (dead after main loop). Total 79360B.
  __shared__ __align__(16) char smem[79360];
  _Float16* Ah   = (_Float16*)smem;
  _Float16* Bh   = (_Float16*)(smem + 33792);
  float4*   comb = (float4*)(smem + 74752);
  int*      codeL= (int*)(smem + 78848);
  float*    sxa  = (float*)(smem + 79104);
  float*    q    = (float*)smem;

  const int tid  = threadIdx.x;
  const int lane = tid & 63;
  const int wid  = tid >> 6;
  const int wr   = wid >> 2;
  const int wc   = wid & 3;
  const int fr   = lane & 15;
  const int fq   = lane >> 4;
  const int wr32 = wr * 32;
  const int fq8  = fq * 8;
  const int n0   = blockIdx.x * 64;
  const int bb   = n0 >> 12;
  const int t0   = n0 & 4095;
  const float NEGI = -1.0f/256.0f;

  const int codeS = tid >> 1;
  const int cOff  = (tid & 1) << 4;

  f16x8_t rb0, rb1;
  {
    const _Float16* p_ = cb16 + (size_t)codeS * DIMS + cOff;
    rb0 = *(const f16x8_t*)(p_); rb1 = *(const f16x8_t*)(p_ + 8);
  }

  // ---- stage A once: 64 rows x 256 c, fp16 ----
  {
    const int dup = tid >> 7;                 // 0..3
    const int c4  = tid & 7;
    const int tt  = ((tid >> 3) & 15) << 2;
    #pragma unroll
    for (int cc2 = 0; cc2 < 2; ++cc2){
      const int c0 = (dup*2 + cc2) * 32;
      const float* xp = x + ((size_t)(bb*DIMS + c0 + c4*4))*NT + t0 + tt;
      float4 va0 = *(const float4*)(xp);
      float4 va1 = *(const float4*)(xp + NT);
      float4 va2 = *(const float4*)(xp + 2*NT);
      float4 va3 = *(const float4*)(xp + 3*NT);
      #pragma unroll
      for (int j = 0; j < 4; ++j){
        f16x4_t p;
        p.x = (_Float16)((&va0.x)[j]);
        p.y = (_Float16)((&va1.x)[j]);
        p.z = (_Float16)((&va2.x)[j]);
        p.w = (_Float16)((&va3.x)[j]);
        *(f16x4_t*)&AH(tt + j, c0 + c4*4) = p;
      }
    }
  }

  const f32x4_t Z = {0.f, 0.f, 0.f, 0.f};
  f32x4_t a00=Z,a01=Z,a02=Z,a03=Z, a10=Z,a11=Z,a12=Z,a13=Z;
  DECL_T2(0,0) DECL_T2(0,1) DECL_T2(0,2) DECL_T2(0,3)
  DECL_T2(1,0) DECL_T2(1,1) DECL_T2(1,2) DECL_T2(1,3)

  const int bC0 = wc*64 + 0*16 + fr;
  const int bC1 = wc*64 + 1*16 + fr;
  const int bC2 = wc*64 + 2*16 + fr;
  const int bC3 = wc*64 + 3*16 + fr;

  for (int kt = 0; kt < 4; ++kt){
    const _Float16* bsrcKt = cb16 + ((size_t)(kt*256) + codeS) * DIMS + cOff;
    BSTEP(0) BSTEP(1) BSTEP(2) BSTEP(3)
    BSTEP(4) BSTEP(5) BSTEP(6) BSTEP(7)

    const int kb  = kt*256 + wc*64 + fr;
    const int kc0 = kb, kc1 = kb + 16, kc2 = kb + 32, kc3 = kb + 48;
    const float ec0 = se[kc0], ec1 = se[kc1], ec2 = se[kc2], ec3 = se[kc3];
    FOLD(0,0) FOLD(0,1) FOLD(0,2) FOLD(0,3)
    FOLD(1,0) FOLD(1,1) FOLD(1,2) FOLD(1,3)
    a00=Z;a01=Z;a02=Z;a03=Z; a10=Z;a11=Z;a12=Z;a13=Z;
  }

  // cross-lane (fr) merge into comb
  MERGE(0,0) MERGE(0,1) MERGE(0,2) MERGE(0,3)
  MERGE(1,0) MERGE(1,1) MERGE(1,2) MERGE(1,3)
  __syncthreads();

  // approx row norms from staged fp16 A (for fused loss; ~1e-4 accuracy is plenty)
  {
    const int row = tid >> 3, seg = tid & 7;
    float s = 0.f;
    #pragma unroll
    for (int k = 0; k < 4; ++k){
      f16x8_t hv = *(const f16x8_t*)&AH(row, seg*32 + k*8);
      #pragma unroll
      for (int e = 0; e < 8; ++e){
        float f = (float)hv[e];
        s = fmaf(f, f, s);
      }
    }
    s += __shfl_xor(s, 1);
    s += __shfl_xor(s, 2);
    s += __shfl_xor(s, 4);
    if (seg == 0) sxa[row] = s;
  }
  __syncthreads();

  if (tid < 64){
    float4 p = comb[tid*4 + 0];
    float v1 = p.x, v2 = p.z;
    int   i1 = __float_as_int(p.y);
    #pragma unroll
    for (int w = 1; w < 4; ++w){
      p = comb[tid*4 + w];
      bool tk = p.x < v1;
      v2 = tk ? fminf(v1, p.z) : fminf(v2, p.x);
      i1 = tk ? __float_as_int(p.y) : i1;
      v1 = tk ? p.x : v1;
    }
    const int r = n0 + tid;
    codeL[tid] = i1;
    out2[r] = (float)i1;
    bool flg = !(v2 - v1 >= THETA);
    if (flg){
      unsigned pos = atomicAdd(cnt, 1u);
      wl[pos] = (unsigned)r;
    }
    // fused loss for unflagged rows: d = ||x||^2 + (se - 2dot) (refine adds flagged)
    double c = flg ? 0.0 : (double)(sxa[tid] + v1);
    #pragma unroll
    for (int m = 1; m < 64; m <<= 1) c += __shfl_xor(c, m);
    if (tid == 0) atomicAdd(accd, c);
  }
  __syncthreads();

  // ---- stage 64 selected fp32 codebook rows into q (aliases Ah/Bh) ----
  {
    const int r = tid >> 3, seg = tid & 7;
    const float* src = cb + (size_t)codeL[r] * DIMS;
    #pragma unroll
    for (int k = 0; k < 8; ++k){
      float4 v = *(const float4*)(src + k*32 + seg*4);
      *(float4*)&QQ(r, k*32 + seg*4) = v;
    }
  }
  __syncthreads();

  // ---- write out0 tile: channel-major, 64B-line coalesced ----
  {
    #pragma unroll
    for (int jj = 0; jj < 2; ++jj){
      const int c = wid*32 + jj*16 + (lane >> 2);
      float* dst = out0 + ((size_t)(bb*256 + c))*NT + t0;
      #pragma unroll
      for (int ii = 0; ii < 4; ++ii){
        const int tl = ii*16 + (lane & 3)*4;
        float4 v;
        v.x = QQ(tl + 0, c);
        v.y = QQ(tl + 1, c);
        v.z = QQ(tl + 2, c);
        v.w = QQ(tl + 3, c);
        *(float4*)(dst + tl) = v;
      }
    }
  }
}

// ---- kernel 2: exact fp32-numpy-emulated re-scan of flagged rows + out0 patch ----
__global__ __launch_bounds__(256) void vq_refine(
    const float* __restrict__ x, const float* __restrict__ cb,
    const float* __restrict__ se,
    const unsigned* __restrict__ wl, const unsigned* __restrict__ cnt,
    float* __restrict__ out2, float* __restrict__ out0, double* __restrict__ accd)
{
  __shared__ float eT[8][1024];   // 32 KiB transposed codebook chunk
  __shared__ float xs[DIMS][8];   // 8 KiB
  __shared__ int   rows_s[8];
  __shared__ float sxs[8];
  __shared__ float wv[4][8];
  __shared__ int   wi[4][8];
  __shared__ int   wiF[8];

  const unsigned n = *cnt;
  const unsigned groups = (n + 7u) >> 3;
  const int tid  = threadIdx.x;
  const int lane = tid & 63;
  const int wid  = tid >> 6;

  for (unsigned g = blockIdx.x; g < groups; g += gridDim.x){
    __syncthreads();   // protect shared reuse across groups
    if (tid < 8){
      unsigned e = g*8u + (unsigned)tid;
      rows_s[tid] = (int)wl[e < n ? e : (n - 1u)];
    }
    __syncthreads();
    // stage x rows (scattered gather along c)
    #pragma unroll
    for (int rep = 0; rep < 8; ++rep){
      int id = rep * 256 + tid;
      int c = id >> 3, r = id & 7;
      int row = rows_s[r];
      int b = row >> 12, t = row & 4095;
      xs[c][r] = x[((size_t)(b*DIMS + c))*NT + t];
    }
    __syncthreads();
    // bit-exact sx per row from xs (numpy pairwise: 8-acc chains + fixed tree)
    if (tid < 128){
      const int r = tid >> 4, hj = tid & 15;
      const int h = hj >> 3, j = hj & 7;
      float v0 = xs[h*128 + j][r];
      float s = __fmul_rn(v0, v0);
      #pragma unroll
      for (int i = 1; i < 16; ++i){
        float v = xs[h*128 + j + 8*i][r];
        s = __fadd_rn(s, __fmul_rn(v, v));
      }
      s = __fadd_rn(s, __shfl_xor(s, 1));
      s = __fadd_rn(s, __shfl_xor(s, 2));
      s = __fadd_rn(s, __shfl_xor(s, 4));
      s = __fadd_rn(s, __shfl_xor(s, 8));
      if (hj == 0) sxs[r] = s;
    }

    float s[8][4];
    #pragma unroll
    for (int r = 0; r < 8; ++r)
      #pragma unroll
      for (int u = 0; u < 4; ++u) s[r][u] = 0.f;

    for (int c0 = 0; c0 < DIMS; c0 += 8){
      __syncthreads();
      #pragma unroll
      for (int rep = 0; rep < 8; ++rep){
        int id2 = rep * 256 + tid;
        int k = id2 >> 1, qq = id2 & 1;
        float4 v = *(const float4*)&cb[(size_t)k * DIMS + c0 + qq * 4];
        eT[qq*4 + 0][k] = v.x; eT[qq*4 + 1][k] = v.y;
        eT[qq*4 + 2][k] = v.z; eT[qq*4 + 3][k] = v.w;
      }
      __syncthreads();
      #pragma unroll
      for (int cc = 0; cc < 8; ++cc){
        float4 ev = *(const float4*)&eT[cc][wid*256 + lane*4];
        #pragma unroll
        for (int r = 0; r < 8; ++r){
          float xv = xs[c0 + cc][r];
          s[r][0] = fmaf(xv, ev.x, s[r][0]);
          s[r][1] = fmaf(xv, ev.y, s[r][1]);
          s[r][2] = fmaf(xv, ev.z, s[r][2]);
          s[r][3] = fmaf(xv, ev.w, s[r][3]);
        }
      }
    }

    float4 sek = *(const float4*)&se[wid*256 + lane*4];
    #pragma unroll
    for (int r = 0; r < 8; ++r){
      const float sxv = sxs[r];
      float bv = 3.4e38f; int bi = 0x7fffffff;
      #pragma unroll
      for (int u = 0; u < 4; ++u){
        float d = __fsub_rn(__fadd_rn(sxv, (&sek.x)[u]),
                            __fadd_rn(s[r][u], s[r][u]));
        int k = wid*256 + lane*4 + u;
        if (d < bv || (d == bv && k < bi)) { bv = d; bi = k; }
      }
      #pragma unroll
      for (int m = 1; m < 64; m <<= 1){
        float ov = __shfl_xor(bv, m);
        int   oi = __shfl_xor(bi, m);
        if (ov < bv || (ov == bv && oi < bi)) { bv = ov; bi = oi; }
      }
      if (lane == 0){ wv[wid][r] = bv; wi[wid][r] = bi; }
    }
    __syncthreads();
    if (tid < 8){
      const int r = tid;
      float bv = wv[0][r]; int bi = wi[0][r];
      #pragma unroll
      for (int w = 1; w < 4; ++w){
        float ov = wv[w][r]; int oi = wi[w][r];
        if (ov < bv || (ov == bv && oi < bi)) { bv = ov; bi = oi; }
      }
      wiF[r] = bi;
      if (g*8u + (unsigned)r < n){
        int row = rows_s[r];
        out2[row] = (float)bi;
        atomicAdd(accd, (double)bv);   // exact loss contribution for flagged row
      }
    }
    __syncthreads();
    // patch out0 for flagged rows (final code may differ from scores' approx pick)
    #pragma unroll
    for (int r = 0; r < 8; ++r){
      if (g*8u + (unsigned)r < n){
        int row  = rows_s[r];
        int code = wiF[r];
        out0[((size_t)((row >> 12)*256 + tid))*NT + (row & 4095)] = cb[(size_t)code*DIMS + tid];
      }
    }
  }
}

__global__ void vq_final(const double* __restrict__ accd, float* __restrict__ out1){
  *out1 = (float)(1.25 * (*accd) * (1.0 / 16777216.0));
}

extern "C" void kernel_launch(void* const* d_in, const int* in_sizes, int n_in,
                              void* d_out, int out_size, void* d_ws, size_t ws_size,
                              hipStream_t stream)
{
  const float* x  = (const float*)d_in[0];
  const float* cb = (const float*)d_in[1];
  float* out  = (float*)d_out;
  float* out0 = out;
  float* out1 = out + (size_t)16777216;   // vq_loss
  float* out2 = out + (size_t)16777217;   // indices as float [65536]

  char* ws = (char*)d_ws;
  double*   accd = (double*)(ws + 0);
  unsigned* cnt  = (unsigned*)(ws + 8);
  float*    se   = (float*)(ws + 64);       // 4 KiB
  unsigned* wl   = (unsigned*)(ws + 4160);  // 256 KiB worklist
  _Float16* cb16 = (_Float16*)(ws + 266304);// 512 KiB fp16 codebook (x512)

  hipMemsetAsync(d_ws, 0, 16, stream);      // zero loss accumulator + worklist count
  vq_prep  <<<dim3(1024), dim3(64),  0, stream>>>(cb, se, cb16);
  vq_scores<<<dim3(1024), dim3(512), 0, stream>>>(x, cb, cb16, se, out0, out2, wl, cnt, accd);
  vq_refine<<<dim3(512),  dim3(256), 0, stream>>>(x, cb, se, wl, cnt, out2, out0, accd);
  vq_final <<<dim3(1),    dim3(1),   0, stream>>>(accd, out1);
}